// Round 1
// baseline (173.915 us; speedup 1.0000x reference)
//
#include <hip/hip_runtime.h>
#include <hip/hip_bf16.h>

typedef __attribute__((ext_vector_type(4))) float f4v;
typedef __attribute__((ext_vector_type(4))) unsigned short u16x4;
typedef __attribute__((ext_vector_type(8))) unsigned short u16x8;
typedef __attribute__((ext_vector_type(8))) __bf16 bf16x8;

#define D_MODEL 1024
#define HDIM 64
#define TSEQ 4096
#define NB 4

__device__ __forceinline__ unsigned short f2bf(float f) {
    union { float f; unsigned u; } v; v.f = f;
    unsigned r = v.u + 0x7FFFu + ((v.u >> 16) & 1u);
    return (unsigned short)(r >> 16);
}
__device__ __forceinline__ float bf2f(unsigned short h) {
    union { unsigned u; float f; } v; v.u = ((unsigned)h) << 16; return v.f;
}
__device__ __forceinline__ bf16x8 ld8(const unsigned short* p) {
    return __builtin_bit_cast(bf16x8, *(const u16x8*)p);
}
__device__ __forceinline__ f4v mfma32(bf16x8 a, bf16x8 b, f4v c) {
    return __builtin_amdgcn_mfma_f32_16x16x32_bf16(a, b, c, 0, 0, 0);
}

// ---------- W transpose + bf16 cast: Wt[m][n][k] ----------
__global__ void prep_wt(const float* __restrict__ Wq, const float* __restrict__ Wk,
                        const float* __restrict__ Wv, unsigned short* __restrict__ Wt)
{
    int m = blockIdx.y;
    const float* W = (m == 0) ? Wq : (m == 1) ? Wk : Wv;
    int idx = blockIdx.x * 256 + threadIdx.x;   // 0 .. 1024*64-1, idx = k*64 + n
    int k = idx >> 6, n = idx & 63;
    Wt[((size_t)m * HDIM + n) * D_MODEL + k] = f2bf(W[idx]);
}

// ---------- QKV projection: x[16384,1024] * W -> bf16 Q/K/V ----------
// grid 512, block 256. Block = 32 rows. Waves: (strip = w&1) x (col-half = w>>1).
// x split into hi+lo bf16 for ~fp19 effective input precision.
__global__ __launch_bounds__(256, 2)
void proj_qkv(const float* __restrict__ x, const unsigned short* __restrict__ Wt,
              const float* __restrict__ bq, const float* __restrict__ bk,
              const float* __restrict__ bv,
              unsigned short* __restrict__ Qo, unsigned short* __restrict__ Ko,
              unsigned short* __restrict__ Vo)
{
    __shared__ unsigned short xhi[32][40];
    __shared__ unsigned short xlo[32][40];
    __shared__ unsigned short wt[3][64][40];   // [mat][n][k-slice] (transposed W)

    const int tid = threadIdx.x;
    const int w = tid >> 6, l = tid & 63;
    const int strip = w & 1, chalf = w >> 1;
    const int row0 = blockIdx.x * 32;

    f4v acc[6];
#pragma unroll
    for (int i = 0; i < 6; ++i) acc[i] = (f4v)0.f;

    for (int k0 = 0; k0 < D_MODEL; k0 += 32) {
        __syncthreads();
        {   // stage x tile [32][32] as hi/lo bf16
            int r = tid >> 3, c4 = (tid & 7) * 4;
            f4v xv = *(const f4v*)(x + (size_t)(row0 + r) * D_MODEL + k0 + c4);
            u16x4 hi, lo;
#pragma unroll
            for (int j = 0; j < 4; ++j) {
                unsigned short h = f2bf(xv[j]);
                hi[j] = h;
                lo[j] = f2bf(xv[j] - bf2f(h));
            }
            *(u16x4*)&xhi[r][c4] = hi;
            *(u16x4*)&xlo[r][c4] = lo;
        }
#pragma unroll
        for (int m = 0; m < 3; ++m) {   // stage Wt tiles (already bf16, already transposed)
            int r = tid >> 2, ch8 = (tid & 3) * 8;
            *(u16x8*)&wt[m][r][ch8] =
                *(const u16x8*)(Wt + ((size_t)m * HDIM + r) * D_MODEL + k0 + ch8);
        }
        __syncthreads();

        bf16x8 ahi = ld8(&xhi[strip * 16 + (l & 15)][8 * (l >> 4)]);
        bf16x8 alo = ld8(&xlo[strip * 16 + (l & 15)][8 * (l >> 4)]);
#pragma unroll
        for (int f = 0; f < 6; ++f) {
            int mc = chalf * 6 + f;   // global col-frag 0..11 -> (mat, nf)
            bf16x8 b = ld8(&wt[mc >> 2][(mc & 3) * 16 + (l & 15)][8 * (l >> 4)]);
            acc[f] = mfma32(ahi, b, acc[f]);
            acc[f] = mfma32(alo, b, acc[f]);
        }
    }

    const float* bias[3] = {bq, bk, bv};
    unsigned short* outp[3] = {Qo, Ko, Vo};
#pragma unroll
    for (int f = 0; f < 6; ++f) {
        int mc = chalf * 6 + f;
        int m = mc >> 2, nf = mc & 3;
        int col = nf * 16 + (l & 15);
        float bb = bias[m][col];
#pragma unroll
        for (int r4 = 0; r4 < 4; ++r4) {
            int row = row0 + strip * 16 + 4 * (l >> 4) + r4;
            outp[m][(size_t)row * HDIM + col] = f2bf(acc[f][r4] + bb);
        }
    }
}

// ---------- flash attention, causal, QB=KB=32 ----------
// grid 512 = 4 batches x 128 q-tiles (biggest tile first for LPT balance).
// 4 waves: (q-strip = w&1) x (kv-parity group = w>>1). Each wave stages its own
// K/V copy (L2-hot) -> no barriers inside the kv loop. Groups merge at the end.
__global__ __launch_bounds__(256, 2)
void attn(const unsigned short* __restrict__ Qg, const unsigned short* __restrict__ Kg,
          const unsigned short* __restrict__ Vg, float* __restrict__ Yg)
{
    __shared__ unsigned short Qs[32][72];
    __shared__ unsigned short Ks[4][32][72];
    __shared__ unsigned short Vt[4][64][40];   // transposed V: [d][kv]
    __shared__ unsigned short Ps[4][16][40];
    __shared__ float Osh[2][16][64];
    __shared__ float Msh[2][16], Lsh[2][16];

    const int tid = threadIdx.x;
    const int w = tid >> 6, l = tid & 63;
    const int s = w & 1, gq = w >> 1;
    const int batch = blockIdx.x & 3;
    const int qt = (TSEQ / 32 - 1) - (blockIdx.x >> 2);

    const size_t qoff = ((size_t)batch * TSEQ + (size_t)qt * 32) * HDIM;
#pragma unroll
    for (int p = 0; p < 2; ++p) {
        int idx = p * 256 + tid;
        int r = idx >> 4, c4 = (idx & 15) * 4;
        *(u16x4*)&Qs[r][c4] = *(const u16x4*)(Qg + qoff + (size_t)r * HDIM + c4);
    }
    __syncthreads();

    bf16x8 qf[2];
#pragma unroll
    for (int c = 0; c < 2; ++c)
        qf[c] = ld8(&Qs[s * 16 + (l & 15)][c * 32 + 8 * (l >> 4)]);

    float mrun[4], lrun[4];
    f4v oacc[4];
#pragma unroll
    for (int i = 0; i < 4; ++i) { mrun[i] = -1e30f; lrun[i] = 0.f; oacc[i] = (f4v)0.f; }

    for (int kt = gq; kt <= qt; kt += 2) {
        const size_t kvoff = ((size_t)batch * TSEQ + (size_t)kt * 32) * HDIM;
#pragma unroll
        for (int p = 0; p < 8; ++p) {   // K tile [32][64] -> LDS (row-major)
            int idx = p * 64 + l;
            int r = idx >> 4, c4 = (idx & 15) * 4;
            *(u16x4*)&Ks[w][r][c4] = *(const u16x4*)(Kg + kvoff + (size_t)r * HDIM + c4);
        }
#pragma unroll
        for (int p = 0; p < 8; ++p) {   // V tile -> LDS transposed
            int idx = p * 64 + l;
            int r = idx >> 4, c4 = (idx & 15) * 4;
            u16x4 vv = *(const u16x4*)(Vg + kvoff + (size_t)r * HDIM + c4);
#pragma unroll
            for (int j = 0; j < 4; ++j) Vt[w][c4 + j][r] = vv[j];
        }

        // S = Q K^T (16 rows x 32 kv per wave)
        f4v sacc[2] = {(f4v)0.f, (f4v)0.f};
#pragma unroll
        for (int c = 0; c < 2; ++c) {
#pragma unroll
            for (int nf = 0; nf < 2; ++nf) {
                bf16x8 kf = ld8(&Ks[w][nf * 16 + (l & 15)][c * 32 + 8 * (l >> 4)]);
                sacc[nf] = mfma32(qf[c], kf, sacc[nf]);
            }
        }

        float sv[2][4];
        const bool diag = (kt == qt);
#pragma unroll
        for (int nf = 0; nf < 2; ++nf)
#pragma unroll
            for (int i = 0; i < 4; ++i) {
                float xx = sacc[nf][i] * 0.125f;
                if (diag) {
                    int row = s * 16 + 4 * (l >> 4) + i;
                    int col = nf * 16 + (l & 15);
                    if (col > row) xx = -1e30f;
                }
                sv[nf][i] = xx;
            }

        // online softmax: row r lives on the 16 lanes sharing (l>>4)
        float pm[4];
#pragma unroll
        for (int i = 0; i < 4; ++i) pm[i] = fmaxf(sv[0][i], sv[1][i]);
#pragma unroll
        for (int off = 1; off < 16; off <<= 1)
#pragma unroll
            for (int i = 0; i < 4; ++i) pm[i] = fmaxf(pm[i], __shfl_xor(pm[i], off));

        float ps[2][4], rs[4];
#pragma unroll
        for (int i = 0; i < 4; ++i) {
            float mnew = fmaxf(mrun[i], pm[i]);
            float sc = __expf(mrun[i] - mnew);
            mrun[i] = mnew;
            float r0 = 0.f;
#pragma unroll
            for (int nf = 0; nf < 2; ++nf) {
                float p = __expf(sv[nf][i] - mnew);
                ps[nf][i] = p; r0 += p;
            }
            rs[i] = r0;
            lrun[i] *= sc;
#pragma unroll
            for (int df = 0; df < 4; ++df) oacc[df][i] *= sc;
        }
#pragma unroll
        for (int off = 1; off < 16; off <<= 1)
#pragma unroll
            for (int i = 0; i < 4; ++i) rs[i] += __shfl_xor(rs[i], off);
#pragma unroll
        for (int i = 0; i < 4; ++i) lrun[i] += rs[i];

        // P: C-layout -> A-layout via wave-private LDS round-trip
#pragma unroll
        for (int nf = 0; nf < 2; ++nf)
#pragma unroll
            for (int i = 0; i < 4; ++i)
                Ps[w][4 * (l >> 4) + i][nf * 16 + (l & 15)] = f2bf(ps[nf][i]);

        bf16x8 pf = ld8(&Ps[w][l & 15][8 * (l >> 4)]);
#pragma unroll
        for (int df = 0; df < 4; ++df) {
            bf16x8 vf = ld8(&Vt[w][df * 16 + (l & 15)][8 * (l >> 4)]);
            oacc[df] = mfma32(pf, vf, oacc[df]);
        }
    }

    // merge even/odd kv groups
    __syncthreads();
    if (gq == 1) {
        if ((l & 15) == 0) {
#pragma unroll
            for (int i = 0; i < 4; ++i) {
                Msh[s][4 * (l >> 4) + i] = mrun[i];
                Lsh[s][4 * (l >> 4) + i] = lrun[i];
            }
        }
#pragma unroll
        for (int df = 0; df < 4; ++df)
#pragma unroll
            for (int i = 0; i < 4; ++i)
                Osh[s][4 * (l >> 4) + i][df * 16 + (l & 15)] = oacc[df][i];
    }
    __syncthreads();
    if (gq == 0) {
        const size_t ybase = ((size_t)batch * TSEQ + (size_t)qt * 32 + s * 16) * HDIM;
#pragma unroll
        for (int i = 0; i < 4; ++i) {
            int row = 4 * (l >> 4) + i;
            float m1 = Msh[s][row], l1 = Lsh[s][row];
            float mm = fmaxf(mrun[i], m1);
            float a0 = __expf(mrun[i] - mm), a1 = __expf(m1 - mm);
            float lt = lrun[i] * a0 + l1 * a1;
            float inv = 1.0f / lt;
#pragma unroll
            for (int df = 0; df < 4; ++df) {
                float o = oacc[df][i] * a0 + Osh[s][row][df * 16 + (l & 15)] * a1;
                Yg[ybase + (size_t)row * HDIM + df * 16 + (l & 15)] = o * inv;
            }
        }
    }
}

extern "C" void kernel_launch(void* const* d_in, const int* in_sizes, int n_in,
                              void* d_out, int out_size, void* d_ws, size_t ws_size,
                              hipStream_t stream)
{
    const float* x  = (const float*)d_in[0];
    const float* Wq = (const float*)d_in[1];
    const float* bq = (const float*)d_in[2];
    const float* Wk = (const float*)d_in[3];
    const float* bk = (const float*)d_in[4];
    const float* Wv = (const float*)d_in[5];
    const float* bv = (const float*)d_in[6];
    float* y = (float*)d_out;

    unsigned short* Qb = (unsigned short*)d_ws;          // 16384*64 bf16
    unsigned short* Kb = Qb + (size_t)16384 * 64;
    unsigned short* Vb = Kb + (size_t)16384 * 64;
    unsigned short* Wt = Vb + (size_t)16384 * 64;        // 3*64*1024 bf16

    prep_wt<<<dim3(256, 3), 256, 0, stream>>>(Wq, Wk, Wv, Wt);
    proj_qkv<<<512, 256, 0, stream>>>(x, Wt, bq, bk, bv, Qb, Kb, Vb);
    attn<<<512, 256, 0, stream>>>(Qb, Kb, Vb, y);
}

// Round 3
// 83.834 us; speedup vs baseline: 2.0745x; 2.0745x over previous
//
#include <hip/hip_runtime.h>
#include <hip/hip_bf16.h>

typedef __attribute__((ext_vector_type(4))) float f4v;
typedef __attribute__((ext_vector_type(16))) float f16v;
typedef __attribute__((ext_vector_type(4))) unsigned short u16x4;
typedef __attribute__((ext_vector_type(8))) unsigned short u16x8;
typedef __attribute__((ext_vector_type(4))) unsigned int u32x4;
typedef __attribute__((ext_vector_type(8))) __bf16 bf16x8;

#define D_MODEL 1024
#define HDIM 64
#define TSEQ 4096
#define QB 32
#define KVB 64
// 1/sqrt(HDIM) * log2(e), folded into Q at projection
#define QSCALE 0.18033688011112042f

__device__ __forceinline__ unsigned short f2bf(float f) {
    union { float f; unsigned u; } v; v.f = f;
    unsigned r = v.u + 0x7FFFu + ((v.u >> 16) & 1u);
    return (unsigned short)(r >> 16);
}
__device__ __forceinline__ float bf2f(unsigned short h) {
    union { unsigned u; float f; } v; v.u = ((unsigned)h) << 16; return v.f;
}
__device__ __forceinline__ bf16x8 ld8(const unsigned short* p) {
    return __builtin_bit_cast(bf16x8, *(const u16x8*)p);
}
__device__ __forceinline__ f4v mfma16(bf16x8 a, bf16x8 b, f4v c) {
    return __builtin_amdgcn_mfma_f32_16x16x32_bf16(a, b, c, 0, 0, 0);
}
__device__ __forceinline__ f16v mfma32(bf16x8 a, bf16x8 b, f16v c) {
    return __builtin_amdgcn_mfma_f32_32x32x16_bf16(a, b, c, 0, 0, 0);
}
__device__ __forceinline__ unsigned cvtpk(float a, float b) {
    unsigned r;
    asm("v_cvt_pk_bf16_f32 %0, %1, %2" : "=v"(r) : "v"(a), "v"(b));
    return r;
}
__device__ __forceinline__ void pswap(unsigned& a, unsigned& b) {
    asm("v_permlane32_swap_b32 %0, %1" : "+v"(a), "+v"(b));
}

// ---------- W transpose + bf16 cast: Wt[m][n][k] ----------
__global__ void prep_wt(const float* __restrict__ Wq, const float* __restrict__ Wk,
                        const float* __restrict__ Wv, unsigned short* __restrict__ Wt)
{
    int m = blockIdx.y;
    const float* W = (m == 0) ? Wq : (m == 1) ? Wk : Wv;
    int idx = blockIdx.x * 256 + threadIdx.x;   // idx = k*64 + n
    int k = idx >> 6, n = idx & 63;
    Wt[((size_t)m * HDIM + n) * D_MODEL + k] = f2bf(W[idx]);
}

// ---------- QKV projection: x[16384,1024] * W -> bf16 Q (scaled), K, V^T ----------
__global__ __launch_bounds__(256, 2)
void proj_qkv(const float* __restrict__ x, const unsigned short* __restrict__ Wt,
              const float* __restrict__ bq, const float* __restrict__ bk,
              const float* __restrict__ bv,
              unsigned short* __restrict__ Qo, unsigned short* __restrict__ Ko,
              unsigned short* __restrict__ Vto)
{
    __shared__ unsigned short xhi[32][40];
    __shared__ unsigned short xlo[32][40];
    __shared__ unsigned short wt[3][64][40];

    const int tid = threadIdx.x;
    const int w = tid >> 6, l = tid & 63;
    const int strip = w & 1, chalf = w >> 1;
    const int row0 = blockIdx.x * 32;

    f4v acc[6];
#pragma unroll
    for (int i = 0; i < 6; ++i) acc[i] = (f4v)0.f;

    for (int k0 = 0; k0 < D_MODEL; k0 += 32) {
        __syncthreads();
        {
            int r = tid >> 3, c4 = (tid & 7) * 4;
            f4v xv = *(const f4v*)(x + (size_t)(row0 + r) * D_MODEL + k0 + c4);
            u16x4 hi, lo;
#pragma unroll
            for (int j = 0; j < 4; ++j) {
                unsigned short hh = f2bf(xv[j]);
                hi[j] = hh;
                lo[j] = f2bf(xv[j] - bf2f(hh));
            }
            *(u16x4*)&xhi[r][c4] = hi;
            *(u16x4*)&xlo[r][c4] = lo;
        }
#pragma unroll
        for (int m = 0; m < 3; ++m) {
            int r = tid >> 2, ch8 = (tid & 3) * 8;
            *(u16x8*)&wt[m][r][ch8] =
                *(const u16x8*)(Wt + ((size_t)m * HDIM + r) * D_MODEL + k0 + ch8);
        }
        __syncthreads();

        bf16x8 ahi = ld8(&xhi[strip * 16 + (l & 15)][8 * (l >> 4)]);
        bf16x8 alo = ld8(&xlo[strip * 16 + (l & 15)][8 * (l >> 4)]);
#pragma unroll
        for (int f = 0; f < 6; ++f) {
            int mc = chalf * 6 + f;
            bf16x8 b = ld8(&wt[mc >> 2][(mc & 3) * 16 + (l & 15)][8 * (l >> 4)]);
            acc[f] = mfma16(ahi, b, acc[f]);
            acc[f] = mfma16(alo, b, acc[f]);
        }
    }

    const float* bias[3] = {bq, bk, bv};
#pragma unroll
    for (int f = 0; f < 6; ++f) {
        int mc = chalf * 6 + f;
        int m = mc >> 2, nf = mc & 3;
        int col = nf * 16 + (l & 15);
        float bb = bias[m][col];
        int rowb = row0 + strip * 16 + 4 * (l >> 4);
        if (m == 0) {
#pragma unroll
            for (int r4 = 0; r4 < 4; ++r4)
                Qo[(size_t)(rowb + r4) * HDIM + col] = f2bf((acc[f][r4] + bb) * QSCALE);
        } else if (m == 1) {
#pragma unroll
            for (int r4 = 0; r4 < 4; ++r4)
                Ko[(size_t)(rowb + r4) * HDIM + col] = f2bf(acc[f][r4] + bb);
        } else {
            // V stored transposed: Vt[batch][d][kv]
            int batch = rowb >> 12, kv = rowb & 4095;
            u16x4 pk;
#pragma unroll
            for (int r4 = 0; r4 < 4; ++r4) pk[r4] = f2bf(acc[f][r4] + bb);
            *(u16x4*)(Vto + ((size_t)batch * HDIM + col) * TSEQ + kv) = pk;
        }
    }
}

// ---------- flash attention, causal, register-resident ----------
// 512 blocks (4 batch x 128 q-tiles, LPT order) x 4 waves.
// Each wave: 32 q-rows (whole tile), kv tiles g, g+4, g+8,... of 64.
// S^T = mfma(K, Q^T): lane c holds the kv-column for q-row c -> in-lane softmax.
// PV computed as O^T = V^T P^T so oacc columns are q = c: the lane's own
// softmax row scales ALL its accumulator regs (this was round-2's bug).
// P -> B-frags via cvt_pk + permlane32_swap. No LDS / barriers in kv loop.
__global__ __launch_bounds__(256, 2)
void attn(const unsigned short* __restrict__ Qg, const unsigned short* __restrict__ Kg,
          const unsigned short* __restrict__ Vtg, float* __restrict__ Yg)
{
    __shared__ float Osm[4][QB][65];
    __shared__ float Msm[4][QB];
    __shared__ float Lsm[4][QB];

    const int tid = threadIdx.x;
    const int g = tid >> 6, l = tid & 63;
    const int h = l >> 5, c = l & 31;
    const int batch = blockIdx.x & 3;
    const int qt = (TSEQ / QB - 1) - (blockIdx.x >> 2);
    const int NT = (qt >> 1) + 1;

    const unsigned short* kbase = Kg + ((size_t)batch * TSEQ + c) * HDIM + 8 * h;
    const unsigned short* vbase = Vtg + ((size_t)batch * HDIM + c) * TSEQ + 8 * h;
    const unsigned short* qbase = Qg + ((size_t)batch * TSEQ + (size_t)qt * QB + c) * HDIM + 8 * h;

    bf16x8 qf[4];
#pragma unroll
    for (int ks = 0; ks < 4; ++ks) qf[ks] = ld8(qbase + 16 * ks);

    f16v oacc[2];
    oacc[0] = (f16v)0.f; oacc[1] = (f16v)0.f;
    float mrun = -1e30f, lrun = 0.f;

    auto kload = [&](bf16x8(&kr)[2][4], int t) {
        const unsigned short* p = kbase + (size_t)t * KVB * HDIM;
#pragma unroll
        for (int tb = 0; tb < 2; ++tb)
#pragma unroll
            for (int ks = 0; ks < 4; ++ks)
                kr[tb][ks] = ld8(p + tb * 32 * HDIM + 16 * ks);
    };

    auto body = [&](bf16x8(&kr)[2][4], bf16x8(&kn)[2][4], int t) {
        const int kvb = t * KVB;
        bf16x8 vr[2][4];
        {
            const unsigned short* p = vbase + kvb;
#pragma unroll
            for (int td = 0; td < 2; ++td)
#pragma unroll
                for (int ku = 0; ku < 4; ++ku)
                    vr[td][ku] = ld8(p + (size_t)td * 32 * TSEQ + 16 * ku);
        }
        // S^T = K Q^T  (two 32-kv tiles)
        f16v sacc[2];
        sacc[0] = (f16v)0.f; sacc[1] = (f16v)0.f;
#pragma unroll
        for (int ks = 0; ks < 4; ++ks) {
            sacc[0] = mfma32(kr[0][ks], qf[ks], sacc[0]);
            sacc[1] = mfma32(kr[1][ks], qf[ks], sacc[1]);
        }
        // prefetch next K tile
        int tn = t + 4; if (tn > NT - 1) tn = NT - 1;
        kload(kn, tn);
        // causal mask (diag tile only)
        if (t == NT - 1) {
            const int off = qt * QB - kvb;
#pragma unroll
            for (int tb = 0; tb < 2; ++tb)
#pragma unroll
                for (int r = 0; r < 16; ++r) {
                    int mv = 32 * tb + (r & 3) + 8 * (r >> 2) + 4 * h - off;
                    if (mv > c) sacc[tb][r] = -1e30f;
                }
        }
        // online softmax (exp2 domain; scale pre-folded into Q)
        float pm = -1e30f;
#pragma unroll
        for (int tb = 0; tb < 2; ++tb)
#pragma unroll
            for (int r = 0; r < 16; ++r) pm = fmaxf(pm, sacc[tb][r]);
        pm = fmaxf(pm, __shfl_xor(pm, 32));
        const float mnew = fmaxf(mrun, pm);
        const float sc = exp2f(mrun - mnew);
        mrun = mnew;
        float rs = 0.f;
        float p[2][16];
#pragma unroll
        for (int tb = 0; tb < 2; ++tb)
#pragma unroll
            for (int r = 0; r < 16; ++r) {
                float e = exp2f(sacc[tb][r] - mnew);
                p[tb][r] = e; rs += e;
            }
        rs += __shfl_xor(rs, 32);
        lrun = lrun * sc + rs;
#pragma unroll
        for (int td = 0; td < 2; ++td)
#pragma unroll
            for (int r = 0; r < 16; ++r) oacc[td][r] *= sc;
        // pack P (C-layout) -> MFMA frags via cvt_pk + permlane32_swap
        bf16x8 pa[4];
#pragma unroll
        for (int tb = 0; tb < 2; ++tb) {
            unsigned wp[8];
#pragma unroll
            for (int i = 0; i < 8; ++i) wp[i] = cvtpk(p[tb][2 * i], p[tb][2 * i + 1]);
            pswap(wp[0], wp[2]); pswap(wp[1], wp[3]);
            pswap(wp[4], wp[6]); pswap(wp[5], wp[7]);
            u32x4 f0 = {wp[0], wp[1], wp[2], wp[3]};
            u32x4 f1 = {wp[4], wp[5], wp[6], wp[7]};
            pa[2 * tb]     = __builtin_bit_cast(bf16x8, f0);
            pa[2 * tb + 1] = __builtin_bit_cast(bf16x8, f1);
        }
        // O^T += V^T P^T  (A = V^T frag, B = P^T frag -> C cols are q = c)
#pragma unroll
        for (int ku = 0; ku < 4; ++ku) {
            oacc[0] = mfma32(vr[0][ku], pa[ku], oacc[0]);
            oacc[1] = mfma32(vr[1][ku], pa[ku], oacc[1]);
        }
    };

    bf16x8 kA[2][4], kB[2][4];
    int t = g;
    if (t < NT) {
        kload(kA, t);
        for (;;) {
            body(kA, kB, t);
            t += 4; if (t >= NT) break;
            body(kB, kA, t);
            t += 4; if (t >= NT) break;
        }
    }

    // write partials to LDS: oacc[td][r] = O^T[d][q=c], d = 32*td + layout-row
#pragma unroll
    for (int td = 0; td < 2; ++td)
#pragma unroll
        for (int r = 0; r < 16; ++r) {
            int d = 32 * td + (r & 3) + 8 * (r >> 2) + 4 * h;
            Osm[g][c][d] = oacc[td][r];
        }
    if (h == 0) { Msm[g][c] = mrun; Lsm[g][c] = lrun; }
    __syncthreads();

    // 4-way merge + coalesced store
    {
        const int q = tid >> 3, d8 = (tid & 7) * 8;
        float m0 = Msm[0][q], m1 = Msm[1][q], m2 = Msm[2][q], m3 = Msm[3][q];
        float mm = fmaxf(fmaxf(m0, m1), fmaxf(m2, m3));
        float a0 = exp2f(m0 - mm), a1 = exp2f(m1 - mm);
        float a2 = exp2f(m2 - mm), a3 = exp2f(m3 - mm);
        float L = a0 * Lsm[0][q] + a1 * Lsm[1][q] + a2 * Lsm[2][q] + a3 * Lsm[3][q];
        float inv = 1.f / L;
        float o[8];
#pragma unroll
        for (int j = 0; j < 8; ++j)
            o[j] = (a0 * Osm[0][q][d8 + j] + a1 * Osm[1][q][d8 + j] +
                    a2 * Osm[2][q][d8 + j] + a3 * Osm[3][q][d8 + j]) * inv;
        float* yp = Yg + ((size_t)batch * TSEQ + (size_t)qt * QB + q) * HDIM + d8;
        *(f4v*)yp = {o[0], o[1], o[2], o[3]};
        *(f4v*)(yp + 4) = {o[4], o[5], o[6], o[7]};
    }
}

extern "C" void kernel_launch(void* const* d_in, const int* in_sizes, int n_in,
                              void* d_out, int out_size, void* d_ws, size_t ws_size,
                              hipStream_t stream)
{
    const float* x  = (const float*)d_in[0];
    const float* Wq = (const float*)d_in[1];
    const float* bq = (const float*)d_in[2];
    const float* Wk = (const float*)d_in[3];
    const float* bk = (const float*)d_in[4];
    const float* Wv = (const float*)d_in[5];
    const float* bv = (const float*)d_in[6];
    float* y = (float*)d_out;

    unsigned short* Qb  = (unsigned short*)d_ws;         // 16384*64 bf16 (scaled)
    unsigned short* Kb  = Qb + (size_t)16384 * 64;
    unsigned short* Vtb = Kb + (size_t)16384 * 64;       // transposed V [4][64][4096]
    unsigned short* Wt  = Vtb + (size_t)16384 * 64;      // 3*64*1024 bf16

    prep_wt<<<dim3(256, 3), 256, 0, stream>>>(Wq, Wk, Wv, Wt);
    proj_qkv<<<512, 256, 0, stream>>>(x, Wt, bq, bk, bv, Qb, Kb, Vtb);
    attn<<<512, 256, 0, stream>>>(Qb, Kb, Vtb, y);
}